// Round 8
// baseline (462.889 us; speedup 1.0000x reference)
//
#include <hip/hip_runtime.h>
#include <hip/hip_bf16.h>

// SentenceEmbedding: 3 parallel BiLSTM branches + time maxpool.
// B=256, T=128, E=256, H=256, 4H=1024. Output [256][1536] f32.
//
// R5: single-poller arrival counter + deferred-drain software pipeline.
//  - x pre-packed in B-frag order (k_embed) -> 8 plain 16B loads/wave/step.
//  - W^T slice in LDS; FULL U^T slice in AGPRs (128 regs) -> U.h is pure
//    register MFMA, no LDS reads.
//  - Exchange: publish stores issued at step tail (no wait); vmcnt(0) drain +
//    tx0 atomic_add + tx0 poll happen after W.x kt0-3 of the NEXT step, so
//    drain/flag latency hides under MFMA work. hq loads issue right after the
//    poll barrier; W.x kt4-7 covers their L3 latency.
//  - One u64 arrival counter per (chain,bg) group, 128B-padded; poll is ONE
//    thread per WG (R4's all-thread poll caused L3 contention regression).

#define NB 256
#define NT 128
#define NE 256
#define NH 256
#define NG 1024

using bf16x8 = __attribute__((ext_vector_type(8))) short;
using f32x4  = __attribute__((ext_vector_type(4))) float;
typedef unsigned long long u64;

// ws layout (bytes)
#define X_OFF   0u           // 16 MB  x2: B-frag order [t][bg][kt][nt][lane][8]
#define WT_OFF  16777216u    // 3 MB   W^T A-frag pack
#define UT_OFF  19922944u    // 3 MB   U^T A-frag pack
#define HB_OFF  23068672u    // 3 MB   h exchange (2 par x 48 grp x 32KB)
#define CNT_OFF 26214400u    // 6 KB   arrival counters (48 x 128B-padded u64)
#define HB_PAR_U64 196608    // u64 per parity

static __device__ __forceinline__ ushort f2bf(float f) {
  union { float f; unsigned u; } v; v.f = f;
  unsigned r = v.u + 0x7fffu + ((v.u >> 16) & 1u);   // RNE
  return (ushort)(r >> 16);
}
static __device__ __forceinline__ float rcp_(float x) { return __builtin_amdgcn_rcpf(x); }
static __device__ __forceinline__ float sigf(float x) { return rcp_(1.f + __expf(-x)); }
static __device__ __forceinline__ float tanhf_(float x) { return 1.f - 2.f * rcp_(__expf(2.f * x) + 1.f); }

// ---------------- embed directly into B-frag order ----------------
// x2 slot tid holds x[b][e0..e0+7], b = bg*64+nt*16+(lane&15), e0 = kt*32+(lane>>4)*8,
// tid = (((t*4+bg)*8+kt)*4+nt)*64+lane.
__global__ void k_embed(const int* __restrict__ tok, const float* __restrict__ emb,
                        ushort* __restrict__ x2) {
  const int tid = blockIdx.x * 256 + threadIdx.x;   // 0..1048575
  const int lane = tid & 63;
  const int nt = (tid >> 6) & 3;
  const int kt = (tid >> 8) & 7;
  const int bg = (tid >> 11) & 3;
  const int t  = tid >> 13;
  const int b  = bg * 64 + nt * 16 + (lane & 15);
  const int e0 = kt * 32 + (lane >> 4) * 8;
  const int tk = tok[b * NT + t];
  const float4 v0 = *(const float4*)(emb + (size_t)tk * NE + e0);
  const float4 v1 = *(const float4*)(emb + (size_t)tk * NE + e0 + 4);
  ushort4 o0, o1;
  o0.x = f2bf(v0.x); o0.y = f2bf(v0.y); o0.z = f2bf(v0.z); o0.w = f2bf(v0.w);
  o1.x = f2bf(v1.x); o1.y = f2bf(v1.y); o1.z = f2bf(v1.z); o1.w = f2bf(v1.w);
  ushort4* dst = (ushort4*)(x2 + (size_t)tid * 8);
  dst[0] = o0; dst[1] = o1;
}

// ---------------- pack W^T / U^T into MFMA A-fragment order ----------------
// M-order within cg: ml = hdl*4 + g so the D-frag's 4 regs are the 4 gates
// of one h-dim. pack[chain][cg][kt][mt][lane][j].
__global__ void k_pack(const float* __restrict__ Wf, const float* __restrict__ Uf,
                       const float* __restrict__ Wb, const float* __restrict__ Ub,
                       ushort* __restrict__ wt, ushort* __restrict__ ut) {
  const int tid = blockIdx.x * 256 + threadIdx.x;   // 0..196607
  const int l = tid & 63;
  const int mt = (tid >> 6) & 7;
  const int kt = (tid >> 9) & 7;
  const int cg = (tid >> 12) & 7;
  const int chain = tid >> 15;                      // 0..5
  const int ll = chain >> 1, dir = chain & 1;
  const int ml = mt * 16 + (l & 15);
  const int hdl = ml >> 2, g = ml & 3;
  const int col = g * 256 + cg * 32 + hdl;
  const int k0 = kt * 32 + ((l >> 4) << 3);
  const float* W = (dir ? Wb : Wf) + (size_t)ll * NE * NG;
  const float* U = (dir ? Ub : Uf) + (size_t)ll * NH * NG;
  ushort vw[8], vu[8];
#pragma unroll
  for (int j = 0; j < 8; ++j) {
    vw[j] = f2bf(W[(size_t)(k0 + j) * NG + col]);
    vu[j] = f2bf(U[(size_t)(k0 + j) * NG + col]);
  }
  ushort4* dw = (ushort4*)(wt + (size_t)tid * 8);
  dw[0] = make_ushort4(vw[0], vw[1], vw[2], vw[3]);
  dw[1] = make_ushort4(vw[4], vw[5], vw[6], vw[7]);
  ushort4* du = (ushort4*)(ut + (size_t)tid * 8);
  du[0] = make_ushort4(vu[0], vu[1], vu[2], vu[3]);
  du[1] = make_ushort4(vu[4], vu[5], vu[6], vu[7]);
}

// ---------------- zero counters (graph-replay safe) ----------------
__global__ void k_init(u64* __restrict__ c) { c[threadIdx.x] = 0ull; }

// ---------------- recurrent kernel: 192 WGs x 512 thr ----------------
// LDS: W 0..64K (frag rows) | pub 64K..72K (2 parities x 4KB)
__global__ __launch_bounds__(512, 2) void k_lstm(
    const ushort* __restrict__ x2, const ushort* __restrict__ wt,
    const ushort* __restrict__ ut, const float* __restrict__ bf_,
    const float* __restrict__ bb_, ushort* __restrict__ hbuf,
    u64* __restrict__ cnt, float* __restrict__ out) {
  __shared__ __align__(16) char smem[73728];

  const int bid = blockIdx.x;
  const int w = (bid & 7) * 24 + (bid >> 3);     // XCD chunking (perf-only)
  const int cg = w & 7, grp = w >> 3;            // grp = chain*4 + bg
  const int chain = grp >> 2, bg = grp & 3;
  const int ll = chain >> 1, dir = chain & 1;
  const int tx = threadIdx.x;
  const int wv = tx >> 6, lane = tx & 63;
  const int mh = wv & 1, nt = wv >> 1;
  const int l15 = lane & 15, hi = lane >> 4;

  // ---- preload W^T slice -> LDS ----
  {
    const bf16x8* wsrc = (const bf16x8*)(wt + (size_t)(chain * 8 + cg) * 32768);
    bf16x8* wdst = (bf16x8*)smem;
#pragma unroll
    for (int i = 0; i < 8; ++i) wdst[i * 512 + tx] = wsrc[i * 512 + tx];
  }
  // ---- preload FULL U^T slice -> regs (AGPR file) ----
  bf16x8 uf[8][4];
#pragma unroll
  for (int kt = 0; kt < 8; ++kt)
#pragma unroll
    for (int q = 0; q < 4; ++q)
      uf[kt][q] = *(const bf16x8*)(ut + ((size_t)((chain * 8 + cg) * 8 + kt) * 8 + mh * 4 + q) * 512 + lane * 8);

  // ---- bias: acc reg r = gate r of h-dim hdl ----
  const float* bias = (dir ? bb_ : bf_) + ll * NG;
  float bias_r[4][4];
#pragma unroll
  for (int q = 0; q < 4; ++q)
#pragma unroll
    for (int r = 0; r < 4; ++r)
      bias_r[q][r] = bias[r * 256 + cg * 32 + mh * 16 + q * 4 + hi];

  // publish LDS byte-offsets within a parity buffer (inverse of consumer B-frag map)
  int pubaddr[4];
#pragma unroll
  for (int q = 0; q < 4; ++q) {
    const int lane2 = l15 | ((mh * 2 + (q >> 1)) << 4);
    const int slot = (q & 1) * 4 + hi;
    pubaddr[q] = 65536 + nt * 1024 + lane2 * 16 + slot * 2;
  }

  float c_[4] = {0.f, 0.f, 0.f, 0.f};
  float hm[4] = {-1e30f, -1e30f, -1e30f, -1e30f};

  u64* cgrp = cnt + grp * 16;        // 128B-padded counter
  u64* hb64 = (u64*)hbuf;
  __syncthreads();   // W LDS ready

  for (int tau = 0; tau < NT; ++tau) {
    // ---- xB loads for this step (plain, L2-resident) ----
    const int t = dir ? (NT - 1 - tau) : tau;
    const ushort* xb_base = x2 + ((size_t)((t * 4 + bg) * 32 + nt)) * 512 + lane * 8;
    bf16x8 xb[8];
#pragma unroll
    for (int kt = 0; kt < 8; ++kt) xb[kt] = *(const bf16x8*)(xb_base + kt * 2048);

    f32x4 acc[4];
#pragma unroll
    for (int q = 0; q < 4; ++q)
      acc[q] = (f32x4){bias_r[q][0], bias_r[q][1], bias_r[q][2], bias_r[q][3]};

    // ---- W.x kt0-3 (no sibling dependency; hides publish drain) ----
#pragma unroll
    for (int kt = 0; kt < 4; ++kt)
#pragma unroll
      for (int q = 0; q < 4; ++q) {
        const bf16x8 wA = *(const bf16x8*)(smem + ((kt * 8 + mh * 4 + q) * 64 + lane) * 16);
        acc[q] = __builtin_amdgcn_mfma_f32_16x16x32_bf16(wA, xb[kt], acc[q], 0, 0, 0);
      }

    // ---- drain own publish(tau-1), signal arrival, poll siblings ----
    if (tau > 0) {
      asm volatile("s_waitcnt vmcnt(0)" ::: "memory");   // publish(tau-1) at L3
      if (tx == 0) {
        __hip_atomic_fetch_add(cgrp, 1ull, __ATOMIC_RELAXED, __HIP_MEMORY_SCOPE_AGENT);
        while (__hip_atomic_load(cgrp, __ATOMIC_RELAXED, __HIP_MEMORY_SCOPE_AGENT) < (u64)(8u * (uint)tau))
          __builtin_amdgcn_s_sleep(1);
      }
      __syncthreads();                                   // (1) h_{tau-1} visible
    }

    // ---- hq loads (L3); latency covered by W.x kt4-7 ----
    u64 hq[16];
    if (tau > 0) {
      const u64* hs = hb64 + (size_t)((tau - 1) & 1) * HB_PAR_U64 + grp * 4096;
#pragma unroll
      for (int kt = 0; kt < 8; ++kt) {
        const int o = (kt * 4 + nt) * 128 + lane * 2;
        hq[kt * 2]     = __hip_atomic_load(hs + o,     __ATOMIC_RELAXED, __HIP_MEMORY_SCOPE_AGENT);
        hq[kt * 2 + 1] = __hip_atomic_load(hs + o + 1, __ATOMIC_RELAXED, __HIP_MEMORY_SCOPE_AGENT);
      }
    }

    // ---- W.x kt4-7 ----
#pragma unroll
    for (int kt = 4; kt < 8; ++kt)
#pragma unroll
      for (int q = 0; q < 4; ++q) {
        const bf16x8 wA = *(const bf16x8*)(smem + ((kt * 8 + mh * 4 + q) * 64 + lane) * 16);
        acc[q] = __builtin_amdgcn_mfma_f32_16x16x32_bf16(wA, xb[kt], acc[q], 0, 0, 0);
      }

    // ---- U.h: pure register MFMA ----
    if (tau > 0) {
#pragma unroll
      for (int kt = 0; kt < 8; ++kt) {
        union { u64 q[2]; bf16x8 v; } u;
        u.q[0] = hq[kt * 2]; u.q[1] = hq[kt * 2 + 1];
#pragma unroll
        for (int q = 0; q < 4; ++q)
          acc[q] = __builtin_amdgcn_mfma_f32_16x16x32_bf16(uf[kt][q], u.v, acc[q], 0, 0, 0);
      }
    }

    // ---- gates (acc[q][r] = gate r) + assemble pub slice in LDS[tau&1] ----
    const int parb = (tau & 1) * 4096;
#pragma unroll
    for (int q = 0; q < 4; ++q) {
      const float iv = sigf(acc[q][0]);
      const float fv = sigf(acc[q][1]);
      const float gv = tanhf_(acc[q][2]);
      const float ov = sigf(acc[q][3]);
      const float cn = fv * c_[q] + iv * gv;
      c_[q] = cn;
      const float hv = ov * tanhf_(cn);
      hm[q] = fmaxf(hm[q], hv);
      *(ushort*)(smem + pubaddr[q] + parb) = f2bf(hv);
    }
    __syncthreads();                                     // (2) pub slice assembled

    // ---- publish h_tau (no wait here; drained next step) ----
    if (tau + 1 < NT) {
      const u64 v = *(const u64*)(smem + 65536 + parb + tx * 8);
      __hip_atomic_store(hb64 + (size_t)(tau & 1) * HB_PAR_U64 + grp * 4096 + cg * 512 + tx,
                         v, __ATOMIC_RELAXED, __HIP_MEMORY_SCOPE_AGENT);
    }
  }

  // ---- maxpool output ----
#pragma unroll
  for (int q = 0; q < 4; ++q) {
    const int b = bg * 64 + nt * 16 + l15;
    const int col = ll * 512 + dir * 256 + cg * 32 + mh * 16 + q * 4 + hi;
    out[(size_t)b * 1536 + col] = hm[q];
  }
}

extern "C" void kernel_launch(void* const* d_in, const int* in_sizes, int n_in,
                              void* d_out, int out_size, void* d_ws, size_t ws_size,
                              hipStream_t stream) {
  (void)in_sizes; (void)n_in; (void)out_size; (void)ws_size;
  const int*   tokens = (const int*)d_in[0];
  const float* Emb    = (const float*)d_in[1];
  const float* Wf     = (const float*)d_in[2];
  const float* Uf     = (const float*)d_in[3];
  const float* bf_    = (const float*)d_in[4];
  const float* Wb     = (const float*)d_in[5];
  const float* Ub     = (const float*)d_in[6];
  const float* bb_    = (const float*)d_in[7];
  float* out = (float*)d_out;

  ushort* x2   = (ushort*)((char*)d_ws + X_OFF);
  ushort* wt   = (ushort*)((char*)d_ws + WT_OFF);
  ushort* ut   = (ushort*)((char*)d_ws + UT_OFF);
  ushort* hbuf = (ushort*)((char*)d_ws + HB_OFF);
  u64*    cnt  = (u64*)((char*)d_ws + CNT_OFF);

  hipLaunchKernelGGL(k_embed, dim3(4096), dim3(256), 0, stream, tokens, Emb, x2);
  hipLaunchKernelGGL(k_pack, dim3(768), dim3(256), 0, stream, Wf, Uf, Wb, Ub, wt, ut);
  hipLaunchKernelGGL(k_init, dim3(1), dim3(768), 0, stream, cnt);
  hipLaunchKernelGGL(k_lstm, dim3(192), dim3(512), 0, stream, x2, wt, ut, bf_, bb_, hbuf, cnt, out);
}

// Round 9
// 449.220 us; speedup vs baseline: 1.0304x; 1.0304x over previous
//
#include <hip/hip_runtime.h>
#include <hip/hip_bf16.h>

// SentenceEmbedding: 3 parallel BiLSTM branches + time maxpool.
// B=256, T=128, E=256, H=256, 4H=1024. Output [256][1536] f32.
//
// R6: tail-signal exchange (drain+tag at step end), per-wave tag polling,
//     no counter RMW, 1 barrier/step.
//  - x pre-packed in B-frag order (k_embed) -> 8 plain 16B loads/wave/step.
//  - W^T slice in LDS; FULL U^T slice in AGPRs -> U.h pure register MFMA.
//  - Publish: gates -> LDS assembly (parity dbuf) -> 8B/thread wide store ->
//    vmcnt(0) -> per-cg value tag (tau+1). All at the step TAIL so sibling
//    tags land while this WG runs its own drain+prefix.
//  - Poll: each wave reads the 8 tags (lanes 0..7, one 32B L3 access),
//    __all(tag >= tau); no barrier after the poll.

#define NB 256
#define NT 128
#define NE 256
#define NH 256
#define NG 1024

using bf16x8 = __attribute__((ext_vector_type(8))) short;
using f32x4  = __attribute__((ext_vector_type(4))) float;
typedef unsigned long long u64;

// ws layout (bytes)
#define X_OFF   0u           // 16 MB  x2: B-frag order [t][bg][kt][nt][lane][8]
#define WT_OFF  16777216u    // 3 MB   W^T A-frag pack
#define UT_OFF  19922944u    // 3 MB   U^T A-frag pack
#define HB_OFF  23068672u    // 3 MB   h exchange (2 par x 48 grp x 32KB)
#define TAG_OFF 26214400u    // 3 KB   tags[48][16] u32 (64B line per group)
#define HB_PAR_U64 196608    // u64 per parity

static __device__ __forceinline__ ushort f2bf(float f) {
  union { float f; unsigned u; } v; v.f = f;
  unsigned r = v.u + 0x7fffu + ((v.u >> 16) & 1u);   // RNE
  return (ushort)(r >> 16);
}
static __device__ __forceinline__ float rcp_(float x) { return __builtin_amdgcn_rcpf(x); }
static __device__ __forceinline__ float sigf(float x) { return rcp_(1.f + __expf(-x)); }
static __device__ __forceinline__ float tanhf_(float x) { return 1.f - 2.f * rcp_(__expf(2.f * x) + 1.f); }

// ---------------- embed directly into B-frag order ----------------
// x2 slot tid holds x[b][e0..e0+7], b = bg*64+nt*16+(lane&15), e0 = kt*32+(lane>>4)*8,
// tid = (((t*4+bg)*8+kt)*4+nt)*64+lane.
__global__ void k_embed(const int* __restrict__ tok, const float* __restrict__ emb,
                        ushort* __restrict__ x2) {
  const int tid = blockIdx.x * 256 + threadIdx.x;   // 0..1048575
  const int lane = tid & 63;
  const int nt = (tid >> 6) & 3;
  const int kt = (tid >> 8) & 7;
  const int bg = (tid >> 11) & 3;
  const int t  = tid >> 13;
  const int b  = bg * 64 + nt * 16 + (lane & 15);
  const int e0 = kt * 32 + (lane >> 4) * 8;
  const int tk = tok[b * NT + t];
  const float4 v0 = *(const float4*)(emb + (size_t)tk * NE + e0);
  const float4 v1 = *(const float4*)(emb + (size_t)tk * NE + e0 + 4);
  ushort4 o0, o1;
  o0.x = f2bf(v0.x); o0.y = f2bf(v0.y); o0.z = f2bf(v0.z); o0.w = f2bf(v0.w);
  o1.x = f2bf(v1.x); o1.y = f2bf(v1.y); o1.z = f2bf(v1.z); o1.w = f2bf(v1.w);
  ushort4* dst = (ushort4*)(x2 + (size_t)tid * 8);
  dst[0] = o0; dst[1] = o1;
}

// ---------------- pack W^T / U^T into MFMA A-fragment order ----------------
// M-order within cg: ml = hdl*4 + g so the D-frag's 4 regs are the 4 gates
// of one h-dim. pack[chain][cg][kt][mt][lane][j].
__global__ void k_pack(const float* __restrict__ Wf, const float* __restrict__ Uf,
                       const float* __restrict__ Wb, const float* __restrict__ Ub,
                       ushort* __restrict__ wt, ushort* __restrict__ ut) {
  const int tid = blockIdx.x * 256 + threadIdx.x;   // 0..196607
  const int l = tid & 63;
  const int mt = (tid >> 6) & 7;
  const int kt = (tid >> 9) & 7;
  const int cg = (tid >> 12) & 7;
  const int chain = tid >> 15;                      // 0..5
  const int ll = chain >> 1, dir = chain & 1;
  const int ml = mt * 16 + (l & 15);
  const int hdl = ml >> 2, g = ml & 3;
  const int col = g * 256 + cg * 32 + hdl;
  const int k0 = kt * 32 + ((l >> 4) << 3);
  const float* W = (dir ? Wb : Wf) + (size_t)ll * NE * NG;
  const float* U = (dir ? Ub : Uf) + (size_t)ll * NH * NG;
  ushort vw[8], vu[8];
#pragma unroll
  for (int j = 0; j < 8; ++j) {
    vw[j] = f2bf(W[(size_t)(k0 + j) * NG + col]);
    vu[j] = f2bf(U[(size_t)(k0 + j) * NG + col]);
  }
  ushort4* dw = (ushort4*)(wt + (size_t)tid * 8);
  dw[0] = make_ushort4(vw[0], vw[1], vw[2], vw[3]);
  dw[1] = make_ushort4(vw[4], vw[5], vw[6], vw[7]);
  ushort4* du = (ushort4*)(ut + (size_t)tid * 8);
  du[0] = make_ushort4(vu[0], vu[1], vu[2], vu[3]);
  du[1] = make_ushort4(vu[4], vu[5], vu[6], vu[7]);
}

// ---------------- zero tags (graph-replay safe) ----------------
__global__ void k_init(uint* __restrict__ p) { p[threadIdx.x] = 0u; }

// ---------------- recurrent kernel: 192 WGs x 512 thr ----------------
// LDS: W 0..64K (frag rows) | pub 64K..72K (2 parities x 4KB)
__global__ __launch_bounds__(512, 2) void k_lstm(
    const ushort* __restrict__ x2, const ushort* __restrict__ wt,
    const ushort* __restrict__ ut, const float* __restrict__ bf_,
    const float* __restrict__ bb_, ushort* __restrict__ hbuf,
    uint* __restrict__ tags, float* __restrict__ out) {
  __shared__ __align__(16) char smem[73728];

  const int bid = blockIdx.x;
  const int w = (bid & 7) * 24 + (bid >> 3);     // XCD chunking (perf-only)
  const int cg = w & 7, grp = w >> 3;            // grp = chain*4 + bg
  const int chain = grp >> 2, bg = grp & 3;
  const int ll = chain >> 1, dir = chain & 1;
  const int tx = threadIdx.x;
  const int wv = tx >> 6, lane = tx & 63;
  const int mh = wv & 1, nt = wv >> 1;
  const int l15 = lane & 15, hi = lane >> 4;

  // ---- preload W^T slice -> LDS ----
  {
    const bf16x8* wsrc = (const bf16x8*)(wt + (size_t)(chain * 8 + cg) * 32768);
    bf16x8* wdst = (bf16x8*)smem;
#pragma unroll
    for (int i = 0; i < 8; ++i) wdst[i * 512 + tx] = wsrc[i * 512 + tx];
  }
  // ---- preload FULL U^T slice -> regs (AGPR file) ----
  bf16x8 uf[8][4];
#pragma unroll
  for (int kt = 0; kt < 8; ++kt)
#pragma unroll
    for (int q = 0; q < 4; ++q)
      uf[kt][q] = *(const bf16x8*)(ut + ((size_t)((chain * 8 + cg) * 8 + kt) * 8 + mh * 4 + q) * 512 + lane * 8);

  // ---- bias: acc reg r = gate r of h-dim hdl ----
  const float* bias = (dir ? bb_ : bf_) + ll * NG;
  float bias_r[4][4];
#pragma unroll
  for (int q = 0; q < 4; ++q)
#pragma unroll
    for (int r = 0; r < 4; ++r)
      bias_r[q][r] = bias[r * 256 + cg * 32 + mh * 16 + q * 4 + hi];

  // publish LDS byte-offsets within a parity buffer (inverse of consumer B-frag map)
  int pubaddr[4];
#pragma unroll
  for (int q = 0; q < 4; ++q) {
    const int lane2 = l15 | ((mh * 2 + (q >> 1)) << 4);
    const int slot = (q & 1) * 4 + hi;
    pubaddr[q] = 65536 + nt * 1024 + lane2 * 16 + slot * 2;
  }

  float c_[4] = {0.f, 0.f, 0.f, 0.f};
  float hm[4] = {-1e30f, -1e30f, -1e30f, -1e30f};

  uint* tag_own = tags + grp * 16 + cg;
  const uint* tag_poll = tags + grp * 16 + (lane & 7);
  u64* hb64 = (u64*)hbuf;
  __syncthreads();   // W LDS ready

  for (int tau = 0; tau < NT; ++tau) {
    // ---- xB loads for this step (plain, L2-resident) ----
    const int t = dir ? (NT - 1 - tau) : tau;
    const ushort* xb_base = x2 + ((size_t)((t * 4 + bg) * 32 + nt)) * 512 + lane * 8;
    bf16x8 xb[8];
#pragma unroll
    for (int kt = 0; kt < 8; ++kt) xb[kt] = *(const bf16x8*)(xb_base + kt * 2048);

    f32x4 acc[4];
#pragma unroll
    for (int q = 0; q < 4; ++q)
      acc[q] = (f32x4){bias_r[q][0], bias_r[q][1], bias_r[q][2], bias_r[q][3]};

    // ---- W.x kt0-3 (no sibling dependency; gives sibling tags time to land) ----
#pragma unroll
    for (int kt = 0; kt < 4; ++kt)
#pragma unroll
      for (int q = 0; q < 4; ++q) {
        const bf16x8 wA = *(const bf16x8*)(smem + ((kt * 8 + mh * 4 + q) * 64 + lane) * 16);
        acc[q] = __builtin_amdgcn_mfma_f32_16x16x32_bf16(wA, xb[kt], acc[q], 0, 0, 0);
      }

    // ---- per-wave tag poll (lanes 0..7 cover all 8 siblings; no barrier) ----
    if (tau > 0) {
      while (!__all(__hip_atomic_load(tag_poll, __ATOMIC_RELAXED, __HIP_MEMORY_SCOPE_AGENT) >= (uint)tau))
        __builtin_amdgcn_s_sleep(1);
      asm volatile("" ::: "memory");   // keep hq loads below the poll
    }

    // ---- hq loads (L3); latency covered by W.x kt4-7 ----
    u64 hq[16];
    if (tau > 0) {
      const u64* hs = hb64 + (size_t)((tau - 1) & 1) * HB_PAR_U64 + grp * 4096;
#pragma unroll
      for (int kt = 0; kt < 8; ++kt) {
        const int o = (kt * 4 + nt) * 128 + lane * 2;
        hq[kt * 2]     = __hip_atomic_load(hs + o,     __ATOMIC_RELAXED, __HIP_MEMORY_SCOPE_AGENT);
        hq[kt * 2 + 1] = __hip_atomic_load(hs + o + 1, __ATOMIC_RELAXED, __HIP_MEMORY_SCOPE_AGENT);
      }
    }

    // ---- W.x kt4-7 ----
#pragma unroll
    for (int kt = 4; kt < 8; ++kt)
#pragma unroll
      for (int q = 0; q < 4; ++q) {
        const bf16x8 wA = *(const bf16x8*)(smem + ((kt * 8 + mh * 4 + q) * 64 + lane) * 16);
        acc[q] = __builtin_amdgcn_mfma_f32_16x16x32_bf16(wA, xb[kt], acc[q], 0, 0, 0);
      }

    // ---- U.h: pure register MFMA ----
    if (tau > 0) {
#pragma unroll
      for (int kt = 0; kt < 8; ++kt) {
        union { u64 q[2]; bf16x8 v; } u;
        u.q[0] = hq[kt * 2]; u.q[1] = hq[kt * 2 + 1];
#pragma unroll
        for (int q = 0; q < 4; ++q)
          acc[q] = __builtin_amdgcn_mfma_f32_16x16x32_bf16(uf[kt][q], u.v, acc[q], 0, 0, 0);
      }
    }

    // ---- gates (acc[q][r] = gate r) + assemble pub slice in LDS[tau&1] ----
    const int parb = (tau & 1) * 4096;
#pragma unroll
    for (int q = 0; q < 4; ++q) {
      const float iv = sigf(acc[q][0]);
      const float fv = sigf(acc[q][1]);
      const float gv = tanhf_(acc[q][2]);
      const float ov = sigf(acc[q][3]);
      const float cn = fv * c_[q] + iv * gv;
      c_[q] = cn;
      const float hv = ov * tanhf_(cn);
      hm[q] = fmaxf(hm[q], hv);
      *(ushort*)(smem + pubaddr[q] + parb) = f2bf(hv);
    }
    __syncthreads();                      // (1) pub slice assembled

    // ---- TAIL: publish h_tau, drain, tag -- before next step's prefix ----
    if (tau + 1 < NT) {
      const u64 v = *(const u64*)(smem + 65536 + parb + tx * 8);
      __hip_atomic_store(hb64 + (size_t)(tau & 1) * HB_PAR_U64 + grp * 4096 + cg * 512 + tx,
                         v, __ATOMIC_RELAXED, __HIP_MEMORY_SCOPE_AGENT);
      asm volatile("s_waitcnt vmcnt(0)" ::: "memory");   // h_tau at coherence point
      if (tx == 0)
        __hip_atomic_store(tag_own, (uint)(tau + 1), __ATOMIC_RELAXED, __HIP_MEMORY_SCOPE_AGENT);
    }
  }

  // ---- maxpool output ----
#pragma unroll
  for (int q = 0; q < 4; ++q) {
    const int b = bg * 64 + nt * 16 + l15;
    const int col = ll * 512 + dir * 256 + cg * 32 + mh * 16 + q * 4 + hi;
    out[(size_t)b * 1536 + col] = hm[q];
  }
}

extern "C" void kernel_launch(void* const* d_in, const int* in_sizes, int n_in,
                              void* d_out, int out_size, void* d_ws, size_t ws_size,
                              hipStream_t stream) {
  (void)in_sizes; (void)n_in; (void)out_size; (void)ws_size;
  const int*   tokens = (const int*)d_in[0];
  const float* Emb    = (const float*)d_in[1];
  const float* Wf     = (const float*)d_in[2];
  const float* Uf     = (const float*)d_in[3];
  const float* bf_    = (const float*)d_in[4];
  const float* Wb     = (const float*)d_in[5];
  const float* Ub     = (const float*)d_in[6];
  const float* bb_    = (const float*)d_in[7];
  float* out = (float*)d_out;

  ushort* x2   = (ushort*)((char*)d_ws + X_OFF);
  ushort* wt   = (ushort*)((char*)d_ws + WT_OFF);
  ushort* ut   = (ushort*)((char*)d_ws + UT_OFF);
  ushort* hbuf = (ushort*)((char*)d_ws + HB_OFF);
  uint*   tags = (uint*)((char*)d_ws + TAG_OFF);

  hipLaunchKernelGGL(k_embed, dim3(4096), dim3(256), 0, stream, tokens, Emb, x2);
  hipLaunchKernelGGL(k_pack, dim3(768), dim3(256), 0, stream, Wf, Uf, Wb, Ub, wt, ut);
  hipLaunchKernelGGL(k_init, dim3(1), dim3(768), 0, stream, tags);
  hipLaunchKernelGGL(k_lstm, dim3(192), dim3(512), 0, stream, x2, wt, ut, bf_, bb_, hbuf, tags, out);
}